// Round 4
// baseline (221.953 us; speedup 1.0000x reference)
//
#include <hip/hip_runtime.h>
#include <hip/hip_bf16.h>

#define CIN   256
#define COUT  32
#define IMG_H 96
#define IMG_W 96
#define HW    (IMG_H*IMG_W)
#define NB    2
#define NV    4
#define VSZ   64
#define NVOX  (VSZ*VSZ*VSZ)

// Kernel 1: 1x1 conv -> channel-last bf16 [b,v,h,w,c].
// Block = 256 thr = 4 waves over 64 px. Wave w owns c-chunk [64w,64w+64):
// every global load is UNIQUE bytes (no 4x redundant issue), batched 16-deep
// through an explicit register array for MLP. Cross-wave reduce via padded LDS.
__global__ __launch_bounds__(256) void conv1x1_kernel(
    const float* __restrict__ features,   // [B,V,CIN,H,W] fp32
    const float* __restrict__ Wp,         // [COUT,CIN]
    const float* __restrict__ bp,         // [COUT]
    __hip_bfloat16* __restrict__ out)     // [B,V,H,W,COUT] bf16
{
    __shared__ float Wt[CIN*COUT];        // [c][o], 32 KiB
    __shared__ float Pp[4*64*36];         // [w][px][cout], px-stride 36 (pad), 36 KiB
    const int tid = threadIdx.x;
    #pragma unroll
    for (int i = 0; i < CIN*COUT/256; ++i) {
        int idx = i*256 + tid;
        Wt[idx] = Wp[(idx & 31)*CIN + (idx >> 5)];
    }
    __syncthreads();

    const int w    = tid >> 6;            // wave -> c-chunk (uniform)
    const int lane = tid & 63;            // pixel
    const int bv   = blockIdx.y;
    const int px0  = blockIdx.x*64;
    const float* f = features + (size_t)bv*CIN*HW + (size_t)(w*64)*HW + px0 + lane;

    float acc[32];
    #pragma unroll
    for (int o = 0; o < 32; ++o) acc[o] = (w == 0) ? bp[o] : 0.f;

    const float* wrow = &Wt[(w*64)*COUT];
    for (int cc = 0; cc < 64; cc += 16) {
        float x[16];
        #pragma unroll
        for (int i = 0; i < 16; ++i)       // 16 independent loads, issued together
            x[i] = f[(size_t)(cc + i)*HW];
        #pragma unroll
        for (int i = 0; i < 16; ++i) {
            const float4* wr = (const float4*)(wrow + (size_t)(cc + i)*COUT);
            const float4 w0 = wr[0], w1 = wr[1], w2 = wr[2], w3 = wr[3];
            const float xi = x[i];
            acc[ 0] += xi*w0.x; acc[ 1] += xi*w0.y; acc[ 2] += xi*w0.z; acc[ 3] += xi*w0.w;
            acc[ 4] += xi*w1.x; acc[ 5] += xi*w1.y; acc[ 6] += xi*w1.z; acc[ 7] += xi*w1.w;
            acc[ 8] += xi*w2.x; acc[ 9] += xi*w2.y; acc[10] += xi*w2.z; acc[11] += xi*w2.w;
            acc[12] += xi*w3.x; acc[13] += xi*w3.y; acc[14] += xi*w3.z; acc[15] += xi*w3.w;
            // second 16 couts
            const float4* wr2 = wr + 4;
            const float4 w4 = wr2[0], w5 = wr2[1], w6 = wr2[2], w7 = wr2[3];
            acc[16] += xi*w4.x; acc[17] += xi*w4.y; acc[18] += xi*w4.z; acc[19] += xi*w4.w;
            acc[20] += xi*w5.x; acc[21] += xi*w5.y; acc[22] += xi*w5.z; acc[23] += xi*w5.w;
            acc[24] += xi*w6.x; acc[25] += xi*w6.y; acc[26] += xi*w6.z; acc[27] += xi*w6.w;
            acc[28] += xi*w7.x; acc[29] += xi*w7.y; acc[30] += xi*w7.z; acc[31] += xi*w7.w;
        }
    }

    #pragma unroll
    for (int j = 0; j < 8; ++j)
        *(float4*)(&Pp[(w*64 + lane)*36 + j*4]) =
            make_float4(acc[4*j], acc[4*j+1], acc[4*j+2], acc[4*j+3]);
    __syncthreads();

    // reduce 4 partials; thread t: px = t>>2, couts [8*(t&3), 8*(t&3)+8)
    const int px = tid >> 2, cg = tid & 3;
    float r[8];
    #pragma unroll
    for (int j = 0; j < 8; ++j) r[j] = 0.f;
    #pragma unroll
    for (int ww = 0; ww < 4; ++ww) {
        const float4* p = (const float4*)(&Pp[(ww*64 + px)*36 + cg*8]);
        const float4 a = p[0], b2 = p[1];
        r[0] += a.x;  r[1] += a.y;  r[2] += a.z;  r[3] += a.w;
        r[4] += b2.x; r[5] += b2.y; r[6] += b2.z; r[7] += b2.w;
    }
    union { uint4 u4; __hip_bfloat16 h[8]; } pk;
    #pragma unroll
    for (int j = 0; j < 8; ++j) pk.h[j] = __float2bfloat16(r[j]);
    *(uint4*)(out + ((size_t)(bv*HW + px0 + px))*COUT + cg*8) = pk.u4;
}

// Kernel 2: 4 lanes/voxel, lane owns 8 channels (one 16B bf16 chunk).
// Branchless: corner weight = 0 when invalid (then exp(0)=1 falls out of the
// softmax denominator automatically). All 16 gathers (4 views x 4 corners)
// issued before any use -> 16-deep memory-level parallelism.
__global__ __launch_bounds__(256) void volgen_kernel(
    const __hip_bfloat16* __restrict__ feats,  // [B,V,H,W,COUT] bf16
    const float* __restrict__ proj,            // [B,V,3,4]
    const float* __restrict__ coords,          // [B,NVOX,3]
    float* __restrict__ out)                   // [B,COUT,NVOX]
{
    __shared__ float T[COUT*65];               // [ch][vox] pad 65
    const int tid = threadIdx.x;
    const int vl  = tid >> 2;                  // local voxel 0..63
    const int cg  = tid & 3;                   // channel oct 0..3
    const int b   = blockIdx.y;
    const int n   = blockIdx.x*64 + vl;

    const float* cp = coords + ((size_t)b*NVOX + n)*3;
    const float X = cp[0], Y = cp[1], Z = cp[2];

    int   off[NV][4];
    float wgt[NV][4];
    #pragma unroll
    for (int v = 0; v < NV; ++v) {
        const float* P = proj + (size_t)(b*NV + v)*12;   // uniform -> scalar
        const float wz = P[8]*X + P[9]*Y + P[10]*Z + P[11];
        const bool  vz = wz > 0.f;
        const float rz = __builtin_amdgcn_rcpf(wz);
        float px = (P[0]*X + P[1]*Y + P[2]*Z + P[3]) * rz * (95.f/96.f);
        float py = (P[4]*X + P[5]*Y + P[6]*Z + P[7]) * rz * (95.f/96.f);
        px = vz ? px : 0.f;  py = vz ? py : 0.f;
        px = fminf(fmaxf(px, -1.0e6f), 1.0e6f);          // kill NaN/inf edge cases
        py = fminf(fmaxf(py, -1.0e6f), 1.0e6f);
        const float fx0 = floorf(px), fy0 = floorf(py);
        const int x0 = (int)fx0, y0 = (int)fy0, x1 = x0+1, y1 = y0+1;
        const float wx1 = px - fx0, wx0 = 1.f - wx1;
        const float wy1 = py - fy0, wy0 = 1.f - wy1;
        const bool vx0 = (unsigned)x0 < (unsigned)IMG_W;
        const bool vx1 = (unsigned)x1 < (unsigned)IMG_W;
        const bool vy0 = (unsigned)y0 < (unsigned)IMG_H;
        const bool vy1 = (unsigned)y1 < (unsigned)IMG_H;
        const int cx0 = min(max(x0, 0), IMG_W-1), cx1 = min(max(x1, 0), IMG_W-1);
        const int cy0 = min(max(y0, 0), IMG_H-1), cy1 = min(max(y1, 0), IMG_H-1);
        const int base = ((b*NV + v)*HW)*COUT + cg*8;
        off[v][0] = base + (cy0*IMG_W + cx0)*COUT;  wgt[v][0] = (vz & vx0 & vy0) ? wx0*wy0 : 0.f;
        off[v][1] = base + (cy0*IMG_W + cx1)*COUT;  wgt[v][1] = (vz & vx1 & vy0) ? wx1*wy0 : 0.f;
        off[v][2] = base + (cy1*IMG_W + cx0)*COUT;  wgt[v][2] = (vz & vx0 & vy1) ? wx0*wy1 : 0.f;
        off[v][3] = base + (cy1*IMG_W + cx1)*COUT;  wgt[v][3] = (vz & vx1 & vy1) ? wx1*wy1 : 0.f;
    }

    uint4 t[NV][4];
    #pragma unroll
    for (int v = 0; v < NV; ++v)
        #pragma unroll
        for (int c = 0; c < 4; ++c)
            t[v][c] = *(const uint4*)(feats + off[v][c]);   // 16 loads in flight

    float A[8], Bs[8];
    #pragma unroll
    for (int j = 0; j < 8; ++j) { A[j] = 0.f; Bs[j] = 0.f; }

    #pragma unroll
    for (int v = 0; v < NV; ++v) {
        float s[8];
        #pragma unroll
        for (int j = 0; j < 8; ++j) s[j] = 0.f;
        #pragma unroll
        for (int c = 0; c < 4; ++c) {
            const float w = wgt[v][c];
            const unsigned tu[4] = { t[v][c].x, t[v][c].y, t[v][c].z, t[v][c].w };
            #pragma unroll
            for (int k = 0; k < 4; ++k) {
                s[2*k]   += w * __uint_as_float(tu[k] << 16);
                s[2*k+1] += w * __uint_as_float(tu[k] & 0xffff0000u);
            }
        }
        #pragma unroll
        for (int j = 0; j < 8; ++j) {
            const float e = __expf(s[j]);                 // all-zero weights -> e=1
            A[j] += e;  Bs[j] += s[j]*e;
        }
    }

    #pragma unroll
    for (int j = 0; j < 8; ++j)
        T[(cg*8 + j)*65 + vl] = Bs[j] * __builtin_amdgcn_rcpf(A[j]);
    __syncthreads();

    const size_t ob = (size_t)b*COUT*NVOX + (size_t)blockIdx.x*64;
    #pragma unroll
    for (int i = 0; i < 8; ++i) {
        const int idx = i*256 + tid;
        const int ch = idx >> 6, vx = idx & 63;
        out[ob + (size_t)ch*NVOX + vx] = T[ch*65 + vx];
    }
}

extern "C" void kernel_launch(void* const* d_in, const int* in_sizes, int n_in,
                              void* d_out, int out_size, void* d_ws, size_t ws_size,
                              hipStream_t stream)
{
    const float* features = (const float*)d_in[0];   // [2,4,256,96,96]
    const float* proj     = (const float*)d_in[1];   // [2,4,3,4]
    const float* coords   = (const float*)d_in[2];   // [2,64,64,64,3]
    const float* Wp       = (const float*)d_in[3];   // [32,256]
    const float* bp       = (const float*)d_in[4];   // [32]
    float* out = (float*)d_out;                      // [2,32,64,64,64]
    __hip_bfloat16* featsT = (__hip_bfloat16*)d_ws;  // [2,4,96,96,32] bf16 = 4.72 MB

    hipLaunchKernelGGL(conv1x1_kernel, dim3(HW/64, NB*NV), dim3(256), 0, stream,
                       features, Wp, bp, featsT);
    hipLaunchKernelGGL(volgen_kernel, dim3(NVOX/64, NB), dim3(256), 0, stream,
                       featsT, proj, coords, out);
}

// Round 5
// 188.936 us; speedup vs baseline: 1.1748x; 1.1748x over previous
//
#include <hip/hip_runtime.h>
#include <hip/hip_bf16.h>

#define CIN   256
#define COUT  32
#define IMG_H 96
#define IMG_W 96
#define HW    (IMG_H*IMG_W)
#define NB    2
#define NV    4
#define VSZ   64
#define NVOX  (VSZ*VSZ*VSZ)

// Kernel 1: 1x1 conv -> channel-last bf16 [b,v,h,w,c].
// Block = 256 thr = 4 waves over the same 64 px; wave og owns couts
// [og*8, og*8+8). Weights are wave-uniform -> forced through the SCALAR path
// (s_load_dwordx8, SGPR-sourced FMAs): zero LDS traffic (R3 was LDS-pipe
// bound: 2048 ds_read_b128 x 12cyc = 24.6k cyc/block). x-loads batched
// 8-deep for MLP. No __shared__, no barriers.
__global__ __launch_bounds__(256) void conv1x1_kernel(
    const float* __restrict__ features,   // [B,V,CIN,H,W] fp32
    const float* __restrict__ Wp,         // [COUT,CIN]
    const float* __restrict__ bp,         // [COUT]
    __hip_bfloat16* __restrict__ out)     // [B,V,H,W,COUT] bf16
{
    const int og   = __builtin_amdgcn_readfirstlane((threadIdx.x >> 6) & 3);
    const int lane = threadIdx.x & 63;
    const int bv   = blockIdx.y;
    const int px   = blockIdx.x*64 + lane;
    const float* f     = features + (size_t)bv*CIN*HW + px;
    const float* wbase = Wp + (size_t)og*8*CIN;     // uniform -> scalar base

    float acc[8];
    #pragma unroll
    for (int j = 0; j < 8; ++j) acc[j] = bp[og*8 + j];   // uniform -> s_load

    for (int cc = 0; cc < CIN; cc += 8) {
        float x[8];
        #pragma unroll
        for (int i = 0; i < 8; ++i)                  // 8 indep coalesced loads
            x[i] = f[(size_t)(cc + i)*HW];
        #pragma unroll
        for (int i = 0; i < 8; ++i) {
            #pragma unroll
            for (int j = 0; j < 8; ++j)              // v_fmac v, s, v
                acc[j] += x[i] * wbase[(size_t)j*CIN + cc + i];
        }
    }

    union { uint4 u4; __hip_bfloat16 h[8]; } pk;
    #pragma unroll
    for (int j = 0; j < 8; ++j) pk.h[j] = __float2bfloat16(acc[j]);
    *(uint4*)(out + ((size_t)(bv*HW + px))*COUT + og*8) = pk.u4;
}

// Kernel 2 (unchanged from R4): 4 lanes/voxel, lane owns 8 channels.
// Branchless corner weights; all 16 gathers issued before any use.
__global__ __launch_bounds__(256) void volgen_kernel(
    const __hip_bfloat16* __restrict__ feats,  // [B,V,H,W,COUT] bf16
    const float* __restrict__ proj,            // [B,V,3,4]
    const float* __restrict__ coords,          // [B,NVOX,3]
    float* __restrict__ out)                   // [B,COUT,NVOX]
{
    __shared__ float T[COUT*65];               // [ch][vox] pad 65
    const int tid = threadIdx.x;
    const int vl  = tid >> 2;                  // local voxel 0..63
    const int cg  = tid & 3;                   // channel oct 0..3
    const int b   = blockIdx.y;
    const int n   = blockIdx.x*64 + vl;

    const float* cp = coords + ((size_t)b*NVOX + n)*3;
    const float X = cp[0], Y = cp[1], Z = cp[2];

    int   off[NV][4];
    float wgt[NV][4];
    #pragma unroll
    for (int v = 0; v < NV; ++v) {
        const float* P = proj + (size_t)(b*NV + v)*12;   // uniform -> scalar
        const float wz = P[8]*X + P[9]*Y + P[10]*Z + P[11];
        const bool  vz = wz > 0.f;
        const float rz = __builtin_amdgcn_rcpf(wz);
        float px = (P[0]*X + P[1]*Y + P[2]*Z + P[3]) * rz * (95.f/96.f);
        float py = (P[4]*X + P[5]*Y + P[6]*Z + P[7]) * rz * (95.f/96.f);
        px = vz ? px : 0.f;  py = vz ? py : 0.f;
        px = fminf(fmaxf(px, -1.0e6f), 1.0e6f);
        py = fminf(fmaxf(py, -1.0e6f), 1.0e6f);
        const float fx0 = floorf(px), fy0 = floorf(py);
        const int x0 = (int)fx0, y0 = (int)fy0, x1 = x0+1, y1 = y0+1;
        const float wx1 = px - fx0, wx0 = 1.f - wx1;
        const float wy1 = py - fy0, wy0 = 1.f - wy1;
        const bool vx0 = (unsigned)x0 < (unsigned)IMG_W;
        const bool vx1 = (unsigned)x1 < (unsigned)IMG_W;
        const bool vy0 = (unsigned)y0 < (unsigned)IMG_H;
        const bool vy1 = (unsigned)y1 < (unsigned)IMG_H;
        const int cx0 = min(max(x0, 0), IMG_W-1), cx1 = min(max(x1, 0), IMG_W-1);
        const int cy0 = min(max(y0, 0), IMG_H-1), cy1 = min(max(y1, 0), IMG_H-1);
        const int base = ((b*NV + v)*HW)*COUT + cg*8;
        off[v][0] = base + (cy0*IMG_W + cx0)*COUT;  wgt[v][0] = (vz & vx0 & vy0) ? wx0*wy0 : 0.f;
        off[v][1] = base + (cy0*IMG_W + cx1)*COUT;  wgt[v][1] = (vz & vx1 & vy0) ? wx1*wy0 : 0.f;
        off[v][2] = base + (cy1*IMG_W + cx0)*COUT;  wgt[v][2] = (vz & vx0 & vy1) ? wx0*wy1 : 0.f;
        off[v][3] = base + (cy1*IMG_W + cx1)*COUT;  wgt[v][3] = (vz & vx1 & vy1) ? wx1*wy1 : 0.f;
    }

    uint4 t[NV][4];
    #pragma unroll
    for (int v = 0; v < NV; ++v)
        #pragma unroll
        for (int c = 0; c < 4; ++c)
            t[v][c] = *(const uint4*)(feats + off[v][c]);   // 16 loads in flight

    float A[8], Bs[8];
    #pragma unroll
    for (int j = 0; j < 8; ++j) { A[j] = 0.f; Bs[j] = 0.f; }

    #pragma unroll
    for (int v = 0; v < NV; ++v) {
        float s[8];
        #pragma unroll
        for (int j = 0; j < 8; ++j) s[j] = 0.f;
        #pragma unroll
        for (int c = 0; c < 4; ++c) {
            const float w = wgt[v][c];
            const unsigned tu[4] = { t[v][c].x, t[v][c].y, t[v][c].z, t[v][c].w };
            #pragma unroll
            for (int k = 0; k < 4; ++k) {
                s[2*k]   += w * __uint_as_float(tu[k] << 16);
                s[2*k+1] += w * __uint_as_float(tu[k] & 0xffff0000u);
            }
        }
        #pragma unroll
        for (int j = 0; j < 8; ++j) {
            const float e = __expf(s[j]);                 // all-zero weights -> e=1
            A[j] += e;  Bs[j] += s[j]*e;
        }
    }

    #pragma unroll
    for (int j = 0; j < 8; ++j)
        T[(cg*8 + j)*65 + vl] = Bs[j] * __builtin_amdgcn_rcpf(A[j]);
    __syncthreads();

    const size_t ob = (size_t)b*COUT*NVOX + (size_t)blockIdx.x*64;
    #pragma unroll
    for (int i = 0; i < 8; ++i) {
        const int idx = i*256 + tid;
        const int ch = idx >> 6, vx = idx & 63;
        out[ob + (size_t)ch*NVOX + vx] = T[ch*65 + vx];
    }
}

extern "C" void kernel_launch(void* const* d_in, const int* in_sizes, int n_in,
                              void* d_out, int out_size, void* d_ws, size_t ws_size,
                              hipStream_t stream)
{
    const float* features = (const float*)d_in[0];   // [2,4,256,96,96]
    const float* proj     = (const float*)d_in[1];   // [2,4,3,4]
    const float* coords   = (const float*)d_in[2];   // [2,64,64,64,3]
    const float* Wp       = (const float*)d_in[3];   // [32,256]
    const float* bp       = (const float*)d_in[4];   // [32]
    float* out = (float*)d_out;                      // [2,32,64,64,64]
    __hip_bfloat16* featsT = (__hip_bfloat16*)d_ws;  // [2,4,96,96,32] bf16 = 4.72 MB

    hipLaunchKernelGGL(conv1x1_kernel, dim3(HW/64, NB*NV), dim3(256), 0, stream,
                       features, Wp, bp, featsT);
    hipLaunchKernelGGL(volgen_kernel, dim3(NVOX/64, NB), dim3(256), 0, stream,
                       featsT, proj, coords, out);
}